// Round 7
// baseline (384.251 us; speedup 1.0000x reference)
//
#include <hip/hip_runtime.h>

#define BS_TOK 16384
#define HD 512
#define IDIM 2048
#define NE 8
#define RT_MAX 264            // max 128-row tiles after per-expert padding
#define CAP (RT_MAX * 128)    // 33792 slots

typedef unsigned short u16;
typedef unsigned int u32;
typedef __attribute__((ext_vector_type(8))) __bf16 bf16x8;
typedef __attribute__((ext_vector_type(4))) float f32x4;

__device__ __forceinline__ u16 f2bf(float f) {
  u32 u = __builtin_bit_cast(u32, f);
  u += 0x7fffu + ((u >> 16) & 1u);
  return (u16)(u >> 16);
}
__device__ __forceinline__ float bflo(u32 u) { return __builtin_bit_cast(float, u << 16); }
__device__ __forceinline__ float bfhi(u32 u) { return __builtin_bit_cast(float, u & 0xffff0000u); }
// gelu tanh-approx via sigmoid identity: 0.5v(1+tanh(c)) == v/(1+e^-2c). Saturation-safe.
__device__ __forceinline__ float gelu_t(float v) {
  float c = 0.7978845608028654f * (v + 0.044715f * v * v * v);
  return v / (1.0f + __expf(-2.0f * c));
}
__device__ __forceinline__ void gload16(const u16* g, u16* l) {
  __builtin_amdgcn_global_load_lds((const __attribute__((address_space(1))) u16*)g,
                                   (__attribute__((address_space(3))) u16*)l, 16, 0, 0);
}

// Merged weight transpose: z<8 -> W1 [512][2048] -> W1T [2048][512];
//                          z>=8 -> W2 [2048][512] -> W2T [512][2048]
__global__ void k_transpose2(const float* __restrict__ W1, u16* __restrict__ W1T,
                             const float* __restrict__ W2, u16* __restrict__ W2T) {
  __shared__ float t[32][33];
  int z = blockIdx.z;
  const float* in; u16* out; int R, C, bx, by;
  if (z < NE) { in = W1; out = W1T; R = HD; C = IDIM; bx = blockIdx.x; by = blockIdx.y; }
  else { in = W2; out = W2T; R = IDIM; C = HD; bx = blockIdx.y; by = blockIdx.x; z -= NE; }
  size_t eb = (size_t)z * HD * IDIM;
  int c0 = bx * 32, r0 = by * 32;
  int tx = threadIdx.x, ty = threadIdx.y;
  #pragma unroll
  for (int j = ty; j < 32; j += 8) t[j][tx] = in[eb + (size_t)(r0 + j) * C + (c0 + tx)];
  __syncthreads();
  #pragma unroll
  for (int j = ty; j < 32; j += 8) out[eb + (size_t)(c0 + j) * R + (r0 + tx)] = f2bf(t[tx][j]);
}

__global__ void k_router(const float* __restrict__ x, const float* __restrict__ Wg,
                         const float* __restrict__ bg, int* __restrict__ top_e,
                         float* __restrict__ top_w, u32* __restrict__ counts,
                         float* __restrict__ Psum, u16* __restrict__ xb) {
  __shared__ float wg_s[HD * NE];
  __shared__ float Pp[NE];
  __shared__ u32 cnt[NE];
  int tid = threadIdx.x;
  if (tid < NE) { Pp[tid] = 0.f; cnt[tid] = 0; }
  for (int i = tid; i < HD * NE; i += 256) wg_s[i] = Wg[i];
  __syncthreads();
  int wv = tid >> 6, lane = tid & 63;
  int t = blockIdx.x * 4 + wv;
  const float4* xr = (const float4*)(x + (size_t)t * HD + lane * 8);
  float4 a = xr[0], b = xr[1];
  u32 p0 = f2bf(a.x) | ((u32)f2bf(a.y) << 16);
  u32 p1 = f2bf(a.z) | ((u32)f2bf(a.w) << 16);
  u32 p2 = f2bf(b.x) | ((u32)f2bf(b.y) << 16);
  u32 p3 = f2bf(b.z) | ((u32)f2bf(b.w) << 16);
  ((uint4*)(xb + (size_t)t * HD))[lane] = make_uint4(p0, p1, p2, p3);

  float acc[NE];
  #pragma unroll
  for (int e = 0; e < NE; ++e) acc[e] = 0.f;
  #pragma unroll
  for (int j = 0; j < 8; ++j) {
    float xv = j < 4 ? (&a.x)[j] : (&b.x)[j - 4];
    int h = lane * 8 + j;
    #pragma unroll
    for (int e = 0; e < NE; ++e) acc[e] += xv * wg_s[h * NE + e];
  }
  #pragma unroll
  for (int off = 32; off > 0; off >>= 1) {
    #pragma unroll
    for (int e = 0; e < NE; ++e) acc[e] += __shfl_down(acc[e], off);
  }
  if (lane == 0) {
    float lg[NE];
    #pragma unroll
    for (int e = 0; e < NE; ++e) lg[e] = acc[e] + bg[e];
    int i1 = 0; float m1 = lg[0];
    #pragma unroll
    for (int e = 1; e < NE; ++e) if (lg[e] > m1) { m1 = lg[e]; i1 = e; }
    int i2 = -1; float m2 = -1e30f;
    #pragma unroll
    for (int e = 0; e < NE; ++e) if (e != i1 && lg[e] > m2) { m2 = lg[e]; i2 = e; }
    float s = 0.f, p[NE];
    #pragma unroll
    for (int e = 0; e < NE; ++e) { p[e] = __expf(lg[e] - m1); s += p[e]; }
    float inv = 1.f / s;
    #pragma unroll
    for (int e = 0; e < NE; ++e) { p[e] *= inv; atomicAdd(&Pp[e], p[e]); }
    float denom = p[i1] + p[i2];
    top_e[2 * t] = i1; top_e[2 * t + 1] = i2;
    top_w[2 * t] = p[i1] / denom; top_w[2 * t + 1] = p[i2] / denom;
    atomicAdd(&cnt[i1], 1u); atomicAdd(&cnt[i2], 1u);
  }
  __syncthreads();
  if (tid < NE) { atomicAdd(&counts[tid], cnt[tid]); atomicAdd(&Psum[tid], Pp[tid]); }
}

__global__ void k_scan(const u32* __restrict__ counts, const float* __restrict__ Psum,
                       u32* __restrict__ padoff, u32* __restrict__ pos, float* __restrict__ out) {
  if (threadIdx.x == 0) {
    u32 off = 0; float loss = 0.f;
    for (int e = 0; e < NE; ++e) {
      padoff[e] = off; pos[e] = off;
      off += ((counts[e] + 127u) / 128u) * 128u;
      loss += ((float)counts[e] / (float)(BS_TOK * 2)) * (Psum[e] / (float)BS_TOK);
    }
    padoff[NE] = off;
    out[(size_t)BS_TOK * HD] = 0.01f * (float)NE * loss;  // balance loss scalar
  }
}

__global__ void k_scatter(const int* __restrict__ top_e, const float* __restrict__ top_w,
                          u32* __restrict__ pos, int* __restrict__ perm_t,
                          float* __restrict__ perm_w, int* __restrict__ inv) {
  int g = blockIdx.x * 256 + threadIdx.x;  // 32768 (token,k) pairs
  int e = top_e[g]; float wgt = top_w[g];
  int lane = threadIdx.x & 63;
  #pragma unroll
  for (int ee = 0; ee < NE; ++ee) {
    unsigned long long m = __ballot(e == ee);
    if (e == ee) {
      int nb = __popcll(m & ((1ull << lane) - 1ull));
      int leader = __ffsll((unsigned long long)m) - 1;
      u32 base = 0;
      if (lane == leader) base = atomicAdd(&pos[ee], (u32)__popcll(m));
      base = __shfl(base, leader);
      int slot = (int)base + nb;
      perm_t[slot] = g >> 1;
      perm_w[slot] = wgt;
      inv[g] = slot;
    }
  }
}

__global__ void k_outinit(const float* __restrict__ x, float* __restrict__ out) {
  size_t i = (size_t)blockIdx.x * 256 + threadIdx.x;
  ((float4*)out)[i] = ((const float4*)x)[i];
}

// 128x128 / BK=64 GEMM, counted-vmcnt 2-buffer pipeline (T3-min + T4), plus
// LDS-staged coalesced epilogue: acc -> f32 LDS tile (stride 130, ~conflict-free)
// -> packed bf16 global_store_dwordx4 (8 stores/thread vs 64 scatter-shorts).
template <int KSTEPS, int NCT, int NTOT, bool GATHER, bool ACT, bool ATOMIC>
__global__ __launch_bounds__(256, 2) void k_gemm(
    const u16* __restrict__ A, int lda, const u16* __restrict__ W,
    const float* __restrict__ bias, const int* __restrict__ perm_t,
    const float* __restrict__ perm_w, const u32* __restrict__ padoff,
    u16* __restrict__ C, float* __restrict__ outA, int rt0) {
  __shared__ __align__(16) char smem[128 * 130 * 4];   // 66560B: As+Bs (64KB) U Es
  u16* As0 = (u16*)smem;                // [8192] buffer 0
  u16* As1 = (u16*)(smem + 16384);      // [8192] buffer 1
  u16* Bs0 = (u16*)(smem + 32768);
  u16* Bs1 = (u16*)(smem + 49152);
  float* Es = (float*)smem;             // epilogue [128][130] f32

  int nb = gridDim.x;
  int b = blockIdx.x;
  int tile = (b & 7) * (nb >> 3) + (b >> 3);   // XCD-chunked (nb % 8 == 0)
  int rt = rt0 + tile / NCT, ct = tile % NCT;
  u32 s0 = (u32)rt * 128u;
  if (rt >= RT_MAX || s0 >= padoff[NE]) return;
  int e = 0;
  #pragma unroll
  for (int k = 1; k < NE; ++k) e += (s0 >= padoff[k]) ? 1 : 0;

  int tid = threadIdx.x;
  int wv = tid >> 6, lane = tid & 63;
  int l15 = lane & 15, lg4 = lane >> 4;
  int wr = wv >> 1, wc = wv & 1;

  int srow = tid >> 3;                 // staging row 0..31 (per inst block of 32)
  int cb = (tid & 7) * 16;             // byte col within 128B row
  int cbs = (cb ^ ((srow & 7) << 4)) >> 1;  // pre-swizzled source elem offset

  const u16* ap[4]; const u16* bp[4];
  #pragma unroll
  for (int i = 0; i < 4; ++i) {
    int r = i * 32 + srow;
    int arow = GATHER ? perm_t[s0 + r] : (int)(s0 + r);
    ap[i] = A + (size_t)arow * lda + cbs;
    bp[i] = W + ((size_t)e * NTOT + ct * 128 + r) * (KSTEPS * 64) + cbs;
  }

  f32x4 acc[4][4] = {};

  // prologue: stage K-steps 0 and 1 (16 loads in flight)
  #pragma unroll
  for (int i = 0; i < 4; ++i) gload16(ap[i], As0 + tid * 8 + i * 2048);
  #pragma unroll
  for (int i = 0; i < 4; ++i) gload16(bp[i], Bs0 + tid * 8 + i * 2048);
  #pragma unroll
  for (int i = 0; i < 4; ++i) gload16(ap[i] + 64, As1 + tid * 8 + i * 2048);
  #pragma unroll
  for (int i = 0; i < 4; ++i) gload16(bp[i] + 64, Bs1 + tid * 8 + i * 2048);
  asm volatile("s_waitcnt vmcnt(8)" ::: "memory");   // K-step 0 landed
  __builtin_amdgcn_sched_barrier(0);
  __builtin_amdgcn_s_barrier();

  for (int ks = 0; ks < KSTEPS; ++ks) {
    int cur = ks & 1;
    const u16* Ab = cur ? As1 : As0;
    const u16* Bb = cur ? Bs1 : Bs0;
    bf16x8 af[2][4], bf[2][4];
    #pragma unroll
    for (int kk = 0; kk < 2; ++kk) {
      #pragma unroll
      for (int f = 0; f < 4; ++f) {
        int ra = wr * 64 + f * 16 + l15;
        af[kk][f] = *(const bf16x8*)((const char*)Ab +
                    (ra * 128 + ((kk * 64 + lg4 * 16) ^ ((ra & 7) << 4))));
        int rb = wc * 64 + f * 16 + l15;
        bf[kk][f] = *(const bf16x8*)((const char*)Bb +
                    (rb * 128 + ((kk * 64 + lg4 * 16) ^ ((rb & 7) << 4))));
      }
    }
    asm volatile("s_waitcnt lgkmcnt(0)" ::: "memory");  // frags in regs
    __builtin_amdgcn_sched_barrier(0);                   // rule #18 fence
    __builtin_amdgcn_s_barrier();                        // all waves done reading buf

    if (ks + 2 < KSTEPS) {            // refill the just-freed buffer
      int k0 = (ks + 2) * 64;
      u16* Ad = cur ? As1 : As0;
      u16* Bd = cur ? Bs1 : Bs0;
      #pragma unroll
      for (int i = 0; i < 4; ++i) gload16(ap[i] + k0, Ad + tid * 8 + i * 2048);
      #pragma unroll
      for (int i = 0; i < 4; ++i) gload16(bp[i] + k0, Bd + tid * 8 + i * 2048);
    }

    __builtin_amdgcn_s_setprio(1);
    #pragma unroll
    for (int kk = 0; kk < 2; ++kk) {
      #pragma unroll
      for (int i = 0; i < 4; ++i)
        #pragma unroll
        for (int j = 0; j < 4; ++j)
          acc[i][j] = __builtin_amdgcn_mfma_f32_16x16x32_bf16(af[kk][i], bf[kk][j], acc[i][j], 0, 0, 0);
    }
    __builtin_amdgcn_s_setprio(0);

    if (ks + 1 < KSTEPS) {
      if (ks + 2 < KSTEPS) {
        asm volatile("s_waitcnt vmcnt(8)" ::: "memory");  // ks+1 landed; ks+2 in flight
      } else {
        asm volatile("s_waitcnt vmcnt(0)" ::: "memory");  // tail: drain last stage
      }
      __builtin_amdgcn_sched_barrier(0);
      __builtin_amdgcn_s_barrier();
    }
  }

  int base_n = ct * 128 + wc * 64;
  float bv[4];
  #pragma unroll
  for (int j = 0; j < 4; ++j) bv[j] = bias[e * NTOT + base_n + j * 16 + l15];

  if (ATOMIC) {
    #pragma unroll
    for (int i = 0; i < 4; ++i) {
      u32 mrow = s0 + wr * 64 + i * 16 + lg4 * 4;
      #pragma unroll
      for (int rr = 0; rr < 4; ++rr) {
        u32 m = mrow + rr;
        int tok = perm_t[m]; float wt = perm_w[m];
        if (wt != 0.f) {
          #pragma unroll
          for (int j = 0; j < 4; ++j) {
            float v = (acc[i][j][rr] + bv[j]) * wt;
            atomicAdd(outA + (size_t)tok * HD + base_n + j * 16 + l15, v);
          }
        }
      }
    }
  } else {
    __syncthreads();   // all waves done with As/Bs -> reuse as Es
    #pragma unroll
    for (int i = 0; i < 4; ++i) {
      int mb = wr * 64 + i * 16 + lg4 * 4;
      #pragma unroll
      for (int rr = 0; rr < 4; ++rr) {
        #pragma unroll
        for (int j = 0; j < 4; ++j) {
          float v = acc[i][j][rr] + bv[j];
          if (ACT) v = gelu_t(v);
          Es[(mb + rr) * 130 + wc * 64 + j * 16 + l15] = v;
        }
      }
    }
    __syncthreads();
    // coalesced packed-bf16 store: task = tid + p*256; row = task>>4, blk = task&15
    #pragma unroll
    for (int p = 0; p < 8; ++p) {
      int idx = tid + p * 256;
      int row = idx >> 4, blk = idx & 15;
      const float* src = Es + row * 130 + blk * 8;
      u32 o0 = (u32)f2bf(src[0]) | ((u32)f2bf(src[1]) << 16);
      u32 o1 = (u32)f2bf(src[2]) | ((u32)f2bf(src[3]) << 16);
      u32 o2 = (u32)f2bf(src[4]) | ((u32)f2bf(src[5]) << 16);
      u32 o3 = (u32)f2bf(src[6]) | ((u32)f2bf(src[7]) << 16);
      *(uint4*)(C + (size_t)(s0 + row) * NTOT + ct * 128 + blk * 8) =
          make_uint4(o0, o1, o2, o3);
    }
  }
}

__global__ void k_final(const float* __restrict__ x, const u16* __restrict__ y,
                        const int* __restrict__ inv, const float* __restrict__ top_w,
                        float* __restrict__ out) {
  int tid = threadIdx.x;
  int t = blockIdx.x * 4 + (tid >> 6);
  int lane = tid & 63;
  int s0 = inv[2 * t], s1 = inv[2 * t + 1];
  float w0 = top_w[2 * t], w1 = top_w[2 * t + 1];
  size_t xo = (size_t)t * HD + lane * 8;
  float4 a = *(const float4*)(x + xo);
  float4 b = *(const float4*)(x + xo + 4);
  uint4 ya = *(const uint4*)(y + (size_t)s0 * HD + lane * 8);
  uint4 yb = *(const uint4*)(y + (size_t)s1 * HD + lane * 8);
  float4 o0, o1;
  o0.x = a.x + w0 * bflo(ya.x) + w1 * bflo(yb.x);
  o0.y = a.y + w0 * bfhi(ya.x) + w1 * bfhi(yb.x);
  o0.z = a.z + w0 * bflo(ya.y) + w1 * bflo(yb.y);
  o0.w = a.w + w0 * bfhi(ya.y) + w1 * bfhi(yb.y);
  o1.x = b.x + w0 * bflo(ya.z) + w1 * bflo(yb.z);
  o1.y = b.y + w0 * bfhi(ya.z) + w1 * bfhi(yb.z);
  o1.z = b.z + w0 * bflo(ya.w) + w1 * bflo(yb.w);
  o1.w = b.w + w0 * bfhi(ya.w) + w1 * bfhi(yb.w);
  *(float4*)(out + xo) = o0;
  *(float4*)(out + xo + 4) = o1;
}

extern "C" void kernel_launch(void* const* d_in, const int* in_sizes, int n_in,
                              void* d_out, int out_size, void* d_ws, size_t ws_size,
                              hipStream_t stream) {
  const float* x  = (const float*)d_in[0];
  const float* Wg = (const float*)d_in[1];
  const float* bg = (const float*)d_in[2];
  const float* W1 = (const float*)d_in[3];
  const float* b1 = (const float*)d_in[4];
  const float* W2 = (const float*)d_in[5];
  const float* b2 = (const float*)d_in[6];
  float* out = (float*)d_out;

  char* w = (char*)d_ws;
  u32* counts  = (u32*)(w + 0);
  u32* pos     = (u32*)(w + 32);
  float* Psum  = (float*)(w + 64);
  u32* padoff  = (u32*)(w + 96);
  int* top_e   = (int*)(w + 256);
  float* top_w = (float*)(w + 256 + 131072);
  int* invm    = (int*)(w + 256 + 2 * 131072);
  int* perm_t  = (int*)(w + 256 + 3 * 131072);            // 135168 B
  float* perm_w = (float*)(w + 256 + 3 * 131072 + 135168);
  u16* xb  = (u16*)(w + 663808);
  u16* W1T = (u16*)(w + 17441024);
  u16* W2T = (u16*)(w + 34218240);
  u16* h   = (u16*)(w + 50995456);
  u16* y   = (u16*)(w + 189407488);  // mode A only

  bool modeA = ws_size >= 224010496ull;
  int T;
  if (modeA) {
    T = RT_MAX;
  } else {
    size_t hspace = ws_size > 50995456ull ? ws_size - 50995456ull : 0;
    T = (int)(hspace / (128ull * IDIM * 2));
    T &= ~1;
    if (T < 2) return;               // insufficient scratch -> loud validation fail
    if (T > RT_MAX) T = RT_MAX;
  }

  // init: counts/pos/Psum/padoff (256B) and perm_t+perm_w (contiguous 270336B)
  hipMemsetAsync(w, 0, 256, stream);
  hipMemsetAsync(w + 393472, 0, 270336, stream);
  k_transpose2<<<dim3(IDIM / 32, HD / 32, 2 * NE), dim3(32, 8), 0, stream>>>(W1, W1T, W2, W2T);
  k_router<<<BS_TOK / 4, 256, 0, stream>>>(x, Wg, bg, top_e, top_w, counts, Psum, xb);
  k_scan<<<1, 64, 0, stream>>>(counts, Psum, padoff, pos, out);
  k_scatter<<<(BS_TOK * 2) / 256, 256, 0, stream>>>(top_e, top_w, pos, perm_t, perm_w, invm);
  if (!modeA) k_outinit<<<(BS_TOK * HD / 4) / 256, 256, 0, stream>>>(x, out);

  int nch = (RT_MAX + T - 1) / T;
  for (int c = 0; c < nch; ++c) {
    int rt0 = c * T;
    u16* hadj = h - (size_t)rt0 * 128 * IDIM;
    k_gemm<8, 16, IDIM, true, true, false><<<T * 16, 256, 0, stream>>>(
        xb, HD, W1T, b1, perm_t, perm_w, padoff, hadj, nullptr, rt0);
    if (modeA) {
      k_gemm<32, 4, HD, false, false, false><<<T * 4, 256, 0, stream>>>(
          hadj, IDIM, W2T, b2, perm_t, perm_w, padoff, y, nullptr, rt0);
    } else {
      k_gemm<32, 4, HD, false, false, true><<<T * 4, 256, 0, stream>>>(
          hadj, IDIM, W2T, b2, perm_t, perm_w, padoff, nullptr, out, rt0);
    }
  }
  if (modeA) k_final<<<BS_TOK / 4, 256, 0, stream>>>(x, y, invm, top_w, out);
}

// Round 9
// 364.678 us; speedup vs baseline: 1.0537x; 1.0537x over previous
//
#include <hip/hip_runtime.h>

#define BS_TOK 16384
#define HD 512
#define IDIM 2048
#define NE 8
#define RT_MAX 264            // max 128-row tiles after per-expert padding
#define CAP (RT_MAX * 128)    // 33792 slots

typedef unsigned short u16;
typedef unsigned int u32;
typedef __attribute__((ext_vector_type(8))) __bf16 bf16x8;
typedef __attribute__((ext_vector_type(4))) float f32x4;

__device__ __forceinline__ u16 f2bf(float f) {
  u32 u = __builtin_bit_cast(u32, f);
  u += 0x7fffu + ((u >> 16) & 1u);
  return (u16)(u >> 16);
}
// 1-instruction RNE f32->bf16 (dup operand; short store keeps low 16 bits)
__device__ __forceinline__ u16 f2bf_hw(float f) {
  u32 r;
  asm("v_cvt_pk_bf16_f32 %0, %1, %2" : "=v"(r) : "v"(f), "v"(f));
  return (u16)r;
}
__device__ __forceinline__ float bflo(u32 u) { return __builtin_bit_cast(float, u << 16); }
__device__ __forceinline__ float bfhi(u32 u) { return __builtin_bit_cast(float, u & 0xffff0000u); }
// gelu tanh-approx: 0.5v(1+tanh(c)) == v*sigmoid(2c); exp via v_exp_f32 (=2^x)
// with folded log2(e): t = -2c*log2e = v*(-2.302558 - 0.1029474 v^2).
// Saturation: v>>0: t->-inf, exp2->0, rcp(1)=1 -> v. v<<0: exp2->inf, rcp->0 -> 0.
__device__ __forceinline__ float gelu_t(float v) {
  float t = v * (-2.302558f - 0.1029474f * v * v);
  return v * __builtin_amdgcn_rcpf(1.0f + __builtin_amdgcn_exp2f(t));
}
__device__ __forceinline__ void gload16(const u16* g, u16* l) {
  __builtin_amdgcn_global_load_lds((const __attribute__((address_space(1))) u16*)g,
                                   (__attribute__((address_space(3))) u16*)l, 16, 0, 0);
}

// Merged weight transpose: z<8 -> W1 [512][2048] -> W1T [2048][512];
//                          z>=8 -> W2 [2048][512] -> W2T [512][2048]
__global__ void k_transpose2(const float* __restrict__ W1, u16* __restrict__ W1T,
                             const float* __restrict__ W2, u16* __restrict__ W2T) {
  __shared__ float t[32][33];
  int z = blockIdx.z;
  const float* in; u16* out; int R, C, bx, by;
  if (z < NE) { in = W1; out = W1T; R = HD; C = IDIM; bx = blockIdx.x; by = blockIdx.y; }
  else { in = W2; out = W2T; R = IDIM; C = HD; bx = blockIdx.y; by = blockIdx.x; z -= NE; }
  size_t eb = (size_t)z * HD * IDIM;
  int c0 = bx * 32, r0 = by * 32;
  int tx = threadIdx.x, ty = threadIdx.y;
  #pragma unroll
  for (int j = ty; j < 32; j += 8) t[j][tx] = in[eb + (size_t)(r0 + j) * C + (c0 + tx)];
  __syncthreads();
  #pragma unroll
  for (int j = ty; j < 32; j += 8) out[eb + (size_t)(c0 + j) * R + (r0 + tx)] = f2bf_hw(t[tx][j]);
}

__global__ void k_router(const float* __restrict__ x, const float* __restrict__ Wg,
                         const float* __restrict__ bg, int* __restrict__ top_e,
                         float* __restrict__ top_w, u32* __restrict__ counts,
                         float* __restrict__ Psum, u16* __restrict__ xb) {
  __shared__ float wg_s[HD * NE];
  __shared__ float Pp[NE];
  __shared__ u32 cnt[NE];
  int tid = threadIdx.x;
  if (tid < NE) { Pp[tid] = 0.f; cnt[tid] = 0; }
  for (int i = tid; i < HD * NE; i += 256) wg_s[i] = Wg[i];
  __syncthreads();
  int wv = tid >> 6, lane = tid & 63;
  int t = blockIdx.x * 4 + wv;
  const float4* xr = (const float4*)(x + (size_t)t * HD + lane * 8);
  float4 a = xr[0], b = xr[1];
  u32 p0 = f2bf(a.x) | ((u32)f2bf(a.y) << 16);
  u32 p1 = f2bf(a.z) | ((u32)f2bf(a.w) << 16);
  u32 p2 = f2bf(b.x) | ((u32)f2bf(b.y) << 16);
  u32 p3 = f2bf(b.z) | ((u32)f2bf(b.w) << 16);
  ((uint4*)(xb + (size_t)t * HD))[lane] = make_uint4(p0, p1, p2, p3);

  float acc[NE];
  #pragma unroll
  for (int e = 0; e < NE; ++e) acc[e] = 0.f;
  #pragma unroll
  for (int j = 0; j < 8; ++j) {
    float xv = j < 4 ? (&a.x)[j] : (&b.x)[j - 4];
    int h = lane * 8 + j;
    #pragma unroll
    for (int e = 0; e < NE; ++e) acc[e] += xv * wg_s[h * NE + e];
  }
  #pragma unroll
  for (int off = 32; off > 0; off >>= 1) {
    #pragma unroll
    for (int e = 0; e < NE; ++e) acc[e] += __shfl_down(acc[e], off);
  }
  if (lane == 0) {
    float lg[NE];
    #pragma unroll
    for (int e = 0; e < NE; ++e) lg[e] = acc[e] + bg[e];
    int i1 = 0; float m1 = lg[0];
    #pragma unroll
    for (int e = 1; e < NE; ++e) if (lg[e] > m1) { m1 = lg[e]; i1 = e; }
    int i2 = -1; float m2 = -1e30f;
    #pragma unroll
    for (int e = 0; e < NE; ++e) if (e != i1 && lg[e] > m2) { m2 = lg[e]; i2 = e; }
    float s = 0.f, p[NE];
    #pragma unroll
    for (int e = 0; e < NE; ++e) { p[e] = __expf(lg[e] - m1); s += p[e]; }
    float inv = 1.f / s;
    #pragma unroll
    for (int e = 0; e < NE; ++e) { p[e] *= inv; atomicAdd(&Pp[e], p[e]); }
    float denom = p[i1] + p[i2];
    top_e[2 * t] = i1; top_e[2 * t + 1] = i2;
    top_w[2 * t] = p[i1] / denom; top_w[2 * t + 1] = p[i2] / denom;
    atomicAdd(&cnt[i1], 1u); atomicAdd(&cnt[i2], 1u);
  }
  __syncthreads();
  if (tid < NE) { atomicAdd(&counts[tid], cnt[tid]); atomicAdd(&Psum[tid], Pp[tid]); }
}

__global__ void k_scan(const u32* __restrict__ counts, const float* __restrict__ Psum,
                       u32* __restrict__ padoff, u32* __restrict__ pos, float* __restrict__ out) {
  if (threadIdx.x == 0) {
    u32 off = 0; float loss = 0.f;
    for (int e = 0; e < NE; ++e) {
      padoff[e] = off; pos[e] = off;
      off += ((counts[e] + 127u) / 128u) * 128u;
      loss += ((float)counts[e] / (float)(BS_TOK * 2)) * (Psum[e] / (float)BS_TOK);
    }
    padoff[NE] = off;
    out[(size_t)BS_TOK * HD] = 0.01f * (float)NE * loss;  // balance loss scalar
  }
}

__global__ void k_scatter(const int* __restrict__ top_e, const float* __restrict__ top_w,
                          u32* __restrict__ pos, int* __restrict__ perm_t,
                          float* __restrict__ perm_w, int* __restrict__ inv) {
  int g = blockIdx.x * 256 + threadIdx.x;  // 32768 (token,k) pairs
  int e = top_e[g]; float wgt = top_w[g];
  int lane = threadIdx.x & 63;
  #pragma unroll
  for (int ee = 0; ee < NE; ++ee) {
    unsigned long long m = __ballot(e == ee);
    if (e == ee) {
      int nb = __popcll(m & ((1ull << lane) - 1ull));
      int leader = __ffsll((unsigned long long)m) - 1;
      u32 base = 0;
      if (lane == leader) base = atomicAdd(&pos[ee], (u32)__popcll(m));
      base = __shfl(base, leader);
      int slot = (int)base + nb;
      perm_t[slot] = g >> 1;
      perm_w[slot] = wgt;
      inv[g] = slot;
    }
  }
}

__global__ void k_outinit(const float* __restrict__ x, float* __restrict__ out) {
  size_t i = (size_t)blockIdx.x * 256 + threadIdx.x;
  ((float4*)out)[i] = ((const float4*)x)[i];
}

// 128x128 / BK=64 GEMM, counted-vmcnt 2-buffer pipeline (T3-min + T4).
// Bias pre-folded into accumulator init (bias[n] is row-invariant).
// Epilogue: lean gelu (exp2+rcp) + 1-instr cvt_pk conversions, scatter stores.
template <int KSTEPS, int NCT, int NTOT, bool GATHER, bool ACT, bool ATOMIC>
__global__ __launch_bounds__(256, 2) void k_gemm(
    const u16* __restrict__ A, int lda, const u16* __restrict__ W,
    const float* __restrict__ bias, const int* __restrict__ perm_t,
    const float* __restrict__ perm_w, const u32* __restrict__ padoff,
    u16* __restrict__ C, float* __restrict__ outA, int rt0) {
  __shared__ u16 As[2][8192], Bs[2][8192];
  int nb = gridDim.x;
  int b = blockIdx.x;
  int tile = (b & 7) * (nb >> 3) + (b >> 3);   // XCD-chunked (nb % 8 == 0)
  int rt = rt0 + tile / NCT, ct = tile % NCT;
  u32 s0 = (u32)rt * 128u;
  if (rt >= RT_MAX || s0 >= padoff[NE]) return;
  int e = 0;
  #pragma unroll
  for (int k = 1; k < NE; ++k) e += (s0 >= padoff[k]) ? 1 : 0;

  int tid = threadIdx.x;
  int wv = tid >> 6, lane = tid & 63;
  int l15 = lane & 15, lg4 = lane >> 4;
  int wr = wv >> 1, wc = wv & 1;

  int srow = tid >> 3;                 // staging row 0..31 (per inst block of 32)
  int cb = (tid & 7) * 16;             // byte col within 128B row
  int cbs = (cb ^ ((srow & 7) << 4)) >> 1;  // pre-swizzled source elem offset

  const u16* ap[4]; const u16* bp[4];
  #pragma unroll
  for (int i = 0; i < 4; ++i) {
    int r = i * 32 + srow;
    int arow = GATHER ? perm_t[s0 + r] : (int)(s0 + r);
    ap[i] = A + (size_t)arow * lda + cbs;
    bp[i] = W + ((size_t)e * NTOT + ct * 128 + r) * (KSTEPS * 64) + cbs;
  }

  int base_n = ct * 128 + wc * 64;
  f32x4 acc[4][4];
  #pragma unroll
  for (int j = 0; j < 4; ++j) {
    float bv = bias[e * NTOT + base_n + j * 16 + l15];
    #pragma unroll
    for (int i = 0; i < 4; ++i) acc[i][j] = f32x4{bv, bv, bv, bv};
  }

  // prologue: stage K-steps 0 and 1 (16 loads in flight)
  #pragma unroll
  for (int i = 0; i < 4; ++i) gload16(ap[i], As[0] + tid * 8 + i * 2048);
  #pragma unroll
  for (int i = 0; i < 4; ++i) gload16(bp[i], Bs[0] + tid * 8 + i * 2048);
  #pragma unroll
  for (int i = 0; i < 4; ++i) gload16(ap[i] + 64, As[1] + tid * 8 + i * 2048);
  #pragma unroll
  for (int i = 0; i < 4; ++i) gload16(bp[i] + 64, Bs[1] + tid * 8 + i * 2048);
  asm volatile("s_waitcnt vmcnt(8)" ::: "memory");   // K-step 0 landed
  __builtin_amdgcn_sched_barrier(0);
  __builtin_amdgcn_s_barrier();

  for (int ks = 0; ks < KSTEPS; ++ks) {
    int cur = ks & 1;
    const u16* Ab = As[cur];
    const u16* Bb = Bs[cur];
    bf16x8 af[2][4], bf[2][4];
    #pragma unroll
    for (int kk = 0; kk < 2; ++kk) {
      #pragma unroll
      for (int f = 0; f < 4; ++f) {
        int ra = wr * 64 + f * 16 + l15;
        af[kk][f] = *(const bf16x8*)((const char*)Ab +
                    (ra * 128 + ((kk * 64 + lg4 * 16) ^ ((ra & 7) << 4))));
        int rb = wc * 64 + f * 16 + l15;
        bf[kk][f] = *(const bf16x8*)((const char*)Bb +
                    (rb * 128 + ((kk * 64 + lg4 * 16) ^ ((rb & 7) << 4))));
      }
    }
    asm volatile("s_waitcnt lgkmcnt(0)" ::: "memory");  // frags in regs
    __builtin_amdgcn_sched_barrier(0);                   // rule #18 fence
    __builtin_amdgcn_s_barrier();                        // all waves done reading buf

    if (ks + 2 < KSTEPS) {            // refill the just-freed buffer
      int k0 = (ks + 2) * 64;
      #pragma unroll
      for (int i = 0; i < 4; ++i) gload16(ap[i] + k0, As[cur] + tid * 8 + i * 2048);
      #pragma unroll
      for (int i = 0; i < 4; ++i) gload16(bp[i] + k0, Bs[cur] + tid * 8 + i * 2048);
    }

    __builtin_amdgcn_s_setprio(1);
    #pragma unroll
    for (int kk = 0; kk < 2; ++kk) {
      #pragma unroll
      for (int i = 0; i < 4; ++i)
        #pragma unroll
        for (int j = 0; j < 4; ++j)
          acc[i][j] = __builtin_amdgcn_mfma_f32_16x16x32_bf16(af[kk][i], bf[kk][j], acc[i][j], 0, 0, 0);
    }
    __builtin_amdgcn_s_setprio(0);

    if (ks + 1 < KSTEPS) {
      if (ks + 2 < KSTEPS) {
        asm volatile("s_waitcnt vmcnt(8)" ::: "memory");  // ks+1 landed; ks+2 in flight
      } else {
        asm volatile("s_waitcnt vmcnt(0)" ::: "memory");  // tail: drain last stage
      }
      __builtin_amdgcn_sched_barrier(0);
      __builtin_amdgcn_s_barrier();
    }
  }

  #pragma unroll
  for (int i = 0; i < 4; ++i) {
    u32 mrow = s0 + wr * 64 + i * 16 + lg4 * 4;
    #pragma unroll
    for (int rr = 0; rr < 4; ++rr) {
      u32 m = mrow + rr;
      if (ATOMIC) {
        int tok = perm_t[m]; float wt = perm_w[m];
        if (wt != 0.f) {
          #pragma unroll
          for (int j = 0; j < 4; ++j) {
            float v = acc[i][j][rr] * wt;   // bias already in acc
            atomicAdd(outA + (size_t)tok * HD + base_n + j * 16 + l15, v);
          }
        }
      } else {
        #pragma unroll
        for (int j = 0; j < 4; ++j) {
          float v = acc[i][j][rr];          // bias already in acc
          if (ACT) v = gelu_t(v);
          C[(size_t)m * NTOT + base_n + j * 16 + l15] = f2bf_hw(v);
        }
      }
    }
  }
}

__global__ void k_final(const float* __restrict__ x, const u16* __restrict__ y,
                        const int* __restrict__ inv, const float* __restrict__ top_w,
                        float* __restrict__ out) {
  int tid = threadIdx.x;
  int t = blockIdx.x * 4 + (tid >> 6);
  int lane = tid & 63;
  int s0 = inv[2 * t], s1 = inv[2 * t + 1];
  float w0 = top_w[2 * t], w1 = top_w[2 * t + 1];
  size_t xo = (size_t)t * HD + lane * 8;
  float4 a = *(const float4*)(x + xo);
  float4 b = *(const float4*)(x + xo + 4);
  uint4 ya = *(const uint4*)(y + (size_t)s0 * HD + lane * 8);
  uint4 yb = *(const uint4*)(y + (size_t)s1 * HD + lane * 8);
  float4 o0, o1;
  o0.x = a.x + w0 * bflo(ya.x) + w1 * bflo(yb.x);
  o0.y = a.y + w0 * bfhi(ya.x) + w1 * bfhi(yb.x);
  o0.z = a.z + w0 * bflo(ya.y) + w1 * bflo(yb.y);
  o0.w = a.w + w0 * bfhi(ya.y) + w1 * bfhi(yb.y);
  o1.x = b.x + w0 * bflo(ya.z) + w1 * bflo(yb.z);
  o1.y = b.y + w0 * bfhi(ya.z) + w1 * bfhi(yb.z);
  o1.z = b.z + w0 * bflo(ya.w) + w1 * bflo(yb.w);
  o1.w = b.w + w0 * bfhi(ya.w) + w1 * bfhi(yb.w);
  *(float4*)(out + xo) = o0;
  *(float4*)(out + xo + 4) = o1;
}

extern "C" void kernel_launch(void* const* d_in, const int* in_sizes, int n_in,
                              void* d_out, int out_size, void* d_ws, size_t ws_size,
                              hipStream_t stream) {
  const float* x  = (const float*)d_in[0];
  const float* Wg = (const float*)d_in[1];
  const float* bg = (const float*)d_in[2];
  const float* W1 = (const float*)d_in[3];
  const float* b1 = (const float*)d_in[4];
  const float* W2 = (const float*)d_in[5];
  const float* b2 = (const float*)d_in[6];
  float* out = (float*)d_out;

  char* w = (char*)d_ws;
  u32* counts  = (u32*)(w + 0);
  u32* pos     = (u32*)(w + 32);
  float* Psum  = (float*)(w + 64);
  u32* padoff  = (u32*)(w + 96);
  int* top_e   = (int*)(w + 256);
  float* top_w = (float*)(w + 256 + 131072);
  int* invm    = (int*)(w + 256 + 2 * 131072);
  int* perm_t  = (int*)(w + 256 + 3 * 131072);            // 135168 B
  float* perm_w = (float*)(w + 256 + 3 * 131072 + 135168);
  u16* xb  = (u16*)(w + 663808);
  u16* W1T = (u16*)(w + 17441024);
  u16* W2T = (u16*)(w + 34218240);
  u16* h   = (u16*)(w + 50995456);
  u16* y   = (u16*)(w + 189407488);  // mode A only

  bool modeA = ws_size >= 224010496ull;
  int T;
  if (modeA) {
    T = RT_MAX;
  } else {
    size_t hspace = ws_size > 50995456ull ? ws_size - 50995456ull : 0;
    T = (int)(hspace / (128ull * IDIM * 2));
    T &= ~1;
    if (T < 2) return;               // insufficient scratch -> loud validation fail
    if (T > RT_MAX) T = RT_MAX;
  }

  // init: counts/pos/Psum/padoff (256B) and perm_t+perm_w (contiguous 270336B)
  (void)hipMemsetAsync(w, 0, 256, stream);
  (void)hipMemsetAsync(w + 393472, 0, 270336, stream);
  k_transpose2<<<dim3(IDIM / 32, HD / 32, 2 * NE), dim3(32, 8), 0, stream>>>(W1, W1T, W2, W2T);
  k_router<<<BS_TOK / 4, 256, 0, stream>>>(x, Wg, bg, top_e, top_w, counts, Psum, xb);
  k_scan<<<1, 64, 0, stream>>>(counts, Psum, padoff, pos, out);
  k_scatter<<<(BS_TOK * 2) / 256, 256, 0, stream>>>(top_e, top_w, pos, perm_t, perm_w, invm);
  if (!modeA) k_outinit<<<(BS_TOK * HD / 4) / 256, 256, 0, stream>>>(x, out);

  int nch = (RT_MAX + T - 1) / T;
  for (int c = 0; c < nch; ++c) {
    int rt0 = c * T;
    u16* hadj = h - (size_t)rt0 * 128 * IDIM;
    k_gemm<8, 16, IDIM, true, true, false><<<T * 16, 256, 0, stream>>>(
        xb, HD, W1T, b1, perm_t, perm_w, padoff, hadj, nullptr, rt0);
    if (modeA) {
      k_gemm<32, 4, HD, false, false, false><<<T * 4, 256, 0, stream>>>(
          hadj, IDIM, W2T, b2, perm_t, perm_w, padoff, y, nullptr, rt0);
    } else {
      k_gemm<32, 4, HD, false, false, true><<<T * 4, 256, 0, stream>>>(
          hadj, IDIM, W2T, b2, perm_t, perm_w, padoff, nullptr, out, rt0);
    }
  }
  if (modeA) k_final<<<BS_TOK / 4, 256, 0, stream>>>(x, y, invm, top_w, out);
}